// Round 6
// baseline (658.883 us; speedup 1.0000x reference)
//
#include <hip/hip_runtime.h>
#include <hip/hip_bf16.h>
#include <math.h>

// Problem constants
#define NB   2048     // batch
#define ND   1024     // dim
#define INV_TEMP 10.0f
#define LAMBDA_CS 0.5f
#define GEMM_BLOCKS 1552

using short8  = __attribute__((ext_vector_type(8))) short;
using floatx4 = __attribute__((ext_vector_type(4))) float;

__device__ __forceinline__ unsigned bf16_rne(float f) {
  union { float f; unsigned u; } v; v.f = f;
  unsigned u = v.u;
  u += 0x7FFFu + ((u >> 16) & 1u);
  return u >> 16;
}
__device__ __forceinline__ int pack2_bf16(float lo, float hi) {
  return (int)((bf16_rne(hi) << 16) | bf16_rne(lo));
}

// ---------------------------------------------------------------------------
// Kernel 1: one WAVE per (array t, row b). Lane i owns k = 16i..16i+15.
//   wave t normalizes row b of array t -> bf16 M[(t*NB+b)*ND], publishes
//   1/norm via LDS; waves 2,3 also hold raw e,k rows and compute the cs-reg
//   norms after one barrier. Also zeroes rowsum/counter for kernel 2.
// ---------------------------------------------------------------------------
__global__ __launch_bounds__(256) void k_prep(
    const float* __restrict__ e, const float* __restrict__ k,
    const float* __restrict__ et, const float* __restrict__ kt,
    const float* __restrict__ ratios,
    ushort* __restrict__ M, float* __restrict__ reg2,
    float* __restrict__ rowsum, unsigned* __restrict__ counter)
{
  const int b = blockIdx.x, tid = threadIdx.x;
  const int wv = tid >> 6, lane = tid & 63;

  if (b < 16) rowsum[b * 256 + tid] = 0.0f;
  if (b == 16 && tid == 0) *counter = 0u;

  const float* src = (wv == 0) ? e : (wv == 1) ? k : (wv == 2) ? et : kt;
  const float4* row = (const float4*)(src + (size_t)b * ND);
  float4 v0 = row[lane * 4 + 0], v1 = row[lane * 4 + 1];
  float4 v2 = row[lane * 4 + 2], v3 = row[lane * 4 + 3];

  // waves 2,3 also need raw e,k rows (L2-hot; issue early)
  float4 e0, e1, e2, e3, k0, k1, k2, k3;
  if (wv >= 2) {
    const float4* re = (const float4*)(e + (size_t)b * ND);
    const float4* rk = (const float4*)(k + (size_t)b * ND);
    e0 = re[lane * 4 + 0]; e1 = re[lane * 4 + 1];
    e2 = re[lane * 4 + 2]; e3 = re[lane * 4 + 3];
    k0 = rk[lane * 4 + 0]; k1 = rk[lane * 4 + 1];
    k2 = rk[lane * 4 + 2]; k3 = rk[lane * 4 + 3];
  }

  float ss = v0.x*v0.x + v0.y*v0.y + v0.z*v0.z + v0.w*v0.w
           + v1.x*v1.x + v1.y*v1.y + v1.z*v1.z + v1.w*v1.w
           + v2.x*v2.x + v2.y*v2.y + v2.z*v2.z + v2.w*v2.w
           + v3.x*v3.x + v3.y*v3.y + v3.z*v3.z + v3.w*v3.w;
  #pragma unroll
  for (int o = 1; o < 64; o <<= 1) ss += __shfl_xor(ss, o);
  const float inv = 1.0f / sqrtf(ss);

  __shared__ float s_inv[4];
  if (lane == 0) s_inv[wv] = inv;

  // pack 16 contiguous bf16 (32 B) per lane: two b128 stores
  int4 w0, w1;
  w0.x = pack2_bf16(v0.x*inv, v0.y*inv); w0.y = pack2_bf16(v0.z*inv, v0.w*inv);
  w0.z = pack2_bf16(v1.x*inv, v1.y*inv); w0.w = pack2_bf16(v1.z*inv, v1.w*inv);
  w1.x = pack2_bf16(v2.x*inv, v2.y*inv); w1.y = pack2_bf16(v2.z*inv, v2.w*inv);
  w1.z = pack2_bf16(v3.x*inv, v3.y*inv); w1.w = pack2_bf16(v3.z*inv, v3.w*inv);
  ushort* dst = M + ((size_t)wv * NB + b) * ND + lane * 16;
  *(int4*)dst       = w0;
  *(int4*)(dst + 8) = w1;

  __syncthreads();

  if (wv >= 2) {
    const float ie = s_inv[0], ik = s_inv[1];
    const float r0 = ratios[b];
    const float ra = (wv == 2) ? r0 : 1.0f - r0;   // coefficient on e
    const float rb = 1.0f - ra;                    // coefficient on k
    float a = 0.f;
    #define REG_ACC(vv, ee, kk) { \
      float d; \
      d = vv.x*inv - (ra*(ee.x*ie) + rb*(kk.x*ik)); a += d*d; \
      d = vv.y*inv - (ra*(ee.y*ie) + rb*(kk.y*ik)); a += d*d; \
      d = vv.z*inv - (ra*(ee.z*ie) + rb*(kk.z*ik)); a += d*d; \
      d = vv.w*inv - (ra*(ee.w*ie) + rb*(kk.w*ik)); a += d*d; }
    REG_ACC(v0, e0, k0) REG_ACC(v1, e1, k1) REG_ACC(v2, e2, k2) REG_ACC(v3, e3, k3)
    #undef REG_ACC
    #pragma unroll
    for (int o = 1; o < 64; o <<= 1) a += __shfl_xor(a, o);
    if (lane == 0) reg2[b * 2 + (wv - 2)] = sqrtf(a);
  }
}

// ---------------------------------------------------------------------------
// Kernel 2: fused bf16 NT-GEMM + exp + row-sum + diag + last-block finale.
//   EXACT R2 GEMM geometry (measured 0 bank conflicts, 84 us):
//   mfma_f32_16x16x32_bf16, BK=32, 128-tile, LDS rows 64 B, b128 fragment
//   reads with (q ^ ((m>>1)&3)) chunk swizzle. NEW: __launch_bounds__(256,6)
//   to raise residency to ~6 blocks/CU so barrier drains overlap across
//   blocks. Symmetric left half: upper-tri blocks only + mirrored col credit.
// ---------------------------------------------------------------------------
__global__ __launch_bounds__(256, 6) void k_gemm(
    const ushort* __restrict__ M,
    float* __restrict__ rowsum,        // [4096], zeroed by k_prep
    float* __restrict__ diag,          // [2][4][2048]; [1][0] unused (mirror)
    const float* __restrict__ reg2,    // [2*NB]
    unsigned* __restrict__ counter,
    float* __restrict__ out)
{
  __shared__ ushort As[128 * 32];
  __shared__ ushort Bs[128 * 32];
  __shared__ float redR[256];
  __shared__ float redC[256];
  __shared__ unsigned s_rank;

  // decode (bx, by): 1024 right-half blocks + 528 upper-tri left-half blocks
  int bx, by;
  {
    int idx = blockIdx.x;
    if (idx < 1024) { by = idx >> 5; bx = 32 + (idx & 31); }
    else {
      int t = idx - 1024; by = 0;
      while (t >= 32 - by) { t -= 32 - by; ++by; }
      bx = by + t;
    }
  }
  const bool sym = (bx < 32) && (bx > by);
  const int j0 = bx * 128;
  const int i0 = by * 128;

  const int tid  = threadIdx.x;
  const int wave = tid >> 6;
  const int lane = tid & 63;
  const int q = lane >> 4;       // quad 0..3
  const int m = lane & 15;       // row/col within 16
  const int wrow = (wave >> 1) * 64;
  const int wcol = (wave & 1) * 64;

  floatx4 acc[4][4] = {};

  // staging: chunk = 16 rows x 64 B; wave w stages chunks {2w,2w+1} of A,B.
  // lane -> row lane>>2, 16B sub-chunk (lane&3) ^ ((srow>>1)&3).
  const int srow = lane >> 2;
  const int scol = (lane & 3) ^ ((srow >> 1) & 3);
  const int c0 = wave * 2, c1 = c0 + 1;

  const ushort* gA = M + (size_t)i0 * ND;
  const ushort* gB = M + (size_t)j0 * ND;

  // fragment LDS offsets (ushort units); swizzle matches staging
  int aoff[4], boff[4];
  #pragma unroll
  for (int x = 0; x < 4; ++x) {
    const int sw = (q ^ ((m >> 1) & 3)) * 8;
    aoff[x] = (wrow + x * 16 + m) * 32 + sw;
    boff[x] = (wcol + x * 16 + m) * 32 + sw;
  }

  for (int k0 = 0; k0 < ND; k0 += 32) {
    __syncthreads();
    {
      const ushort* g = gA + (size_t)(c0 * 16 + srow) * ND + k0 + scol * 8;
      __builtin_amdgcn_global_load_lds(
          (const __attribute__((address_space(1))) unsigned int*)g,
          (__attribute__((address_space(3))) unsigned int*)&As[c0 * 512], 16, 0, 0);
    }
    {
      const ushort* g = gA + (size_t)(c1 * 16 + srow) * ND + k0 + scol * 8;
      __builtin_amdgcn_global_load_lds(
          (const __attribute__((address_space(1))) unsigned int*)g,
          (__attribute__((address_space(3))) unsigned int*)&As[c1 * 512], 16, 0, 0);
    }
    {
      const ushort* g = gB + (size_t)(c0 * 16 + srow) * ND + k0 + scol * 8;
      __builtin_amdgcn_global_load_lds(
          (const __attribute__((address_space(1))) unsigned int*)g,
          (__attribute__((address_space(3))) unsigned int*)&Bs[c0 * 512], 16, 0, 0);
    }
    {
      const ushort* g = gB + (size_t)(c1 * 16 + srow) * ND + k0 + scol * 8;
      __builtin_amdgcn_global_load_lds(
          (const __attribute__((address_space(1))) unsigned int*)g,
          (__attribute__((address_space(3))) unsigned int*)&Bs[c1 * 512], 16, 0, 0);
    }
    __syncthreads();

    short8 af[4], bf[4];
    #pragma unroll
    for (int x = 0; x < 4; ++x) {
      af[x] = *(const short8*)&As[aoff[x]];
      bf[x] = *(const short8*)&Bs[boff[x]];
    }
    #pragma unroll
    for (int mi = 0; mi < 4; ++mi)
      #pragma unroll
      for (int ni = 0; ni < 4; ++ni)
        acc[mi][ni] = __builtin_amdgcn_mfma_f32_16x16x32_bf16(
            af[mi], bf[ni], acc[mi][ni], 0, 0, 0);
  }

  // Epilogue. C/D layout: col = lane&15, row = q*4 + reg  [m89/m91]
  float colAcc[4] = {0.f, 0.f, 0.f, 0.f};
  #pragma unroll
  for (int mi = 0; mi < 4; ++mi) {
    #pragma unroll
    for (int r = 0; r < 4; ++r) {
      const int ig = i0 + wrow + mi * 16 + q * 4 + r;
      float s = 0.f;
      #pragma unroll
      for (int ni = 0; ni < 4; ++ni) {
        float v = __expf(acc[mi][ni][r] * INV_TEMP);
        s += v;
        colAcc[ni] += v;
        const int jg = j0 + wcol + ni * 16 + m;
        if ((jg & (NB - 1)) == (ig & (NB - 1))) {
          diag[(((ig >> 11) << 2) + (jg >> 11)) * NB + (ig & (NB - 1))] = v;
        }
      }
      s += __shfl_xor(s, 1);
      s += __shfl_xor(s, 2);
      s += __shfl_xor(s, 4);
      s += __shfl_xor(s, 8);
      if (m == 0) redR[(wave & 1) * 128 + wrow + mi * 16 + q * 4 + r] = s;
    }
  }
  #pragma unroll
  for (int ni = 0; ni < 4; ++ni) {
    float c = colAcc[ni];
    c += __shfl_xor(c, 16);
    c += __shfl_xor(c, 32);
    if (q == 0) redC[(wave >> 1) * 128 + wcol + ni * 16 + m] = c;
  }
  __syncthreads();
  if (tid < 128) {
    atomicAdd(&rowsum[i0 + tid], redR[tid] + redR[128 + tid]);
    if (sym)
      atomicAdd(&rowsum[j0 + tid], redC[tid] + redC[128 + tid]);
  }

  // completion: last finished block computes the final scalars
  __syncthreads();
  if (tid == 0) {
    __threadfence();
    s_rank = __hip_atomic_fetch_add(counter, 1u, __ATOMIC_ACQ_REL,
                                    __HIP_MEMORY_SCOPE_AGENT);
  }
  __syncthreads();
  if (s_rank == GEMM_BLOCKS - 1) {
    float l = 0.f, g = 0.f;
    #pragma unroll
    for (int i = 0; i < 8; ++i) {
      const int n = tid + i * 256;
      float se = __hip_atomic_load(&rowsum[n],        __ATOMIC_RELAXED, __HIP_MEMORY_SCOPE_AGENT);
      float sk = __hip_atomic_load(&rowsum[2048 + n], __ATOMIC_RELAXED, __HIP_MEMORY_SCOPE_AGENT);
      float d_ee  = __hip_atomic_load(&diag[0 * NB + n], __ATOMIC_RELAXED, __HIP_MEMORY_SCOPE_AGENT);
      float d_ek  = __hip_atomic_load(&diag[1 * NB + n], __ATOMIC_RELAXED, __HIP_MEMORY_SCOPE_AGENT);
      float d_eet = __hip_atomic_load(&diag[2 * NB + n], __ATOMIC_RELAXED, __HIP_MEMORY_SCOPE_AGENT);
      float d_ekt = __hip_atomic_load(&diag[3 * NB + n], __ATOMIC_RELAXED, __HIP_MEMORY_SCOPE_AGENT);
      float d_kk  = __hip_atomic_load(&diag[5 * NB + n], __ATOMIC_RELAXED, __HIP_MEMORY_SCOPE_AGENT);
      float d_ket = __hip_atomic_load(&diag[6 * NB + n], __ATOMIC_RELAXED, __HIP_MEMORY_SCOPE_AGENT);
      float d_kkt = __hip_atomic_load(&diag[7 * NB + n], __ATOMIC_RELAXED, __HIP_MEMORY_SCOPE_AGENT);
      float num_e = d_ek + d_eet + d_ekt;
      float den_e = se - d_ee;
      float num_k = d_ek + d_ket + d_kkt;   // k.e diag == e.k diag (mirror)
      float den_k = sk - d_kk;
      l += logf(den_e / num_e) + logf(den_k / num_k);
      g += reg2[2 * n] + reg2[2 * n + 1];
    }
    #pragma unroll
    for (int o = 1; o < 64; o <<= 1) { l += __shfl_xor(l, o); g += __shfl_xor(g, o); }
    if ((tid & 63) == 0) { redR[tid >> 6] = l; redC[tid >> 6] = g; }
    __syncthreads();
    if (tid == 0) {
      float contrastive = (redR[0] + redR[1] + redR[2] + redR[3]) * (1.0f / (2.0f * NB));
      float cs = (redC[0] + redC[1] + redC[2] + redC[3]) * (1.0f / NB);
      out[0] = contrastive + LAMBDA_CS * cs;
      out[1] = contrastive;
      out[2] = cs;
    }
  }
}

// ---------------------------------------------------------------------------
extern "C" void kernel_launch(void* const* d_in, const int* in_sizes, int n_in,
                              void* d_out, int out_size, void* d_ws, size_t ws_size,
                              hipStream_t stream) {
  const float* english = (const float*)d_in[0];
  const float* etok    = (const float*)d_in[1];
  const float* ktoe    = (const float*)d_in[2];
  const float* korean  = (const float*)d_in[3];
  const float* ratios  = (const float*)d_in[4];

  char* ws = (char*)d_ws;
  const size_t OFF_M    = 0;                                   // 8192*1024*2 = 16 MB
  const size_t OFF_RS   = OFF_M + (size_t)8192 * 1024 * 2;     // 4096*4
  const size_t OFF_DIAG = OFF_RS + 4096 * sizeof(float);       // 8*2048*4
  const size_t OFF_REG  = OFF_DIAG + 8 * NB * sizeof(float);   // 2*2048*4
  const size_t OFF_CNT  = OFF_REG + 2 * NB * sizeof(float);    // 4

  ushort* M           = (ushort*)(ws + OFF_M);
  float* rowsum       = (float*)(ws + OFF_RS);
  float* diag         = (float*)(ws + OFF_DIAG);
  float* reg2         = (float*)(ws + OFF_REG);
  unsigned* counter   = (unsigned*)(ws + OFF_CNT);

  k_prep<<<dim3(NB), 256, 0, stream>>>(english, korean, etok, ktoe, ratios,
                                       M, reg2, rowsum, counter);
  k_gemm<<<dim3(GEMM_BLOCKS), 256, 0, stream>>>(M, rowsum, diag, reg2,
                                                counter, (float*)d_out);
}

// Round 7
// 633.087 us; speedup vs baseline: 1.0407x; 1.0407x over previous
//
#include <hip/hip_runtime.h>
#include <hip/hip_bf16.h>
#include <math.h>

// Problem constants
#define NB   2048     // batch
#define ND   1024     // dim
#define INV_TEMP 10.0f
#define LAMBDA_CS 0.5f
#define GEMM_BLOCKS 1552
#define PREP_TASKS 8192   // one task = normalize one row of M

using short8  = __attribute__((ext_vector_type(8))) short;
using floatx4 = __attribute__((ext_vector_type(4))) float;

__device__ __forceinline__ unsigned bf16_rne(float f) {
  union { float f; unsigned u; } v; v.f = f;
  unsigned u = v.u;
  u += 0x7FFFu + ((u >> 16) & 1u);
  return u >> 16;
}
__device__ __forceinline__ int pack2_bf16(float lo, float hi) {
  return (int)((bf16_rne(hi) << 16) | bf16_rne(lo));
}

// ---------------------------------------------------------------------------
// k_init: zero rowsum[4096], grp[64], prep_ticket, done_counter (ws poisoned)
// ---------------------------------------------------------------------------
__global__ __launch_bounds__(256) void k_init(
    float* __restrict__ rowsum, unsigned* __restrict__ grp,
    unsigned* __restrict__ tickets)
{
  const int b = blockIdx.x, tid = threadIdx.x;
  if (b < 16) rowsum[b * 256 + tid] = 0.0f;
  else if (tid < 64) grp[tid] = 0u;
  else if (tid < 66) tickets[tid - 64] = 0u;
}

// ---------------------------------------------------------------------------
// k_main: work-steal prep (normalize -> bf16 M) + flag-gated bf16 NT-GEMM
// (R2's exact measured-0-conflict 84us geometry) + exp/rowsum/diag epilogue +
// last-block finale computing all three outputs (cs-reg from Gram diagonals).
// ---------------------------------------------------------------------------
__global__ __launch_bounds__(256) void k_main(
    const float* __restrict__ e, const float* __restrict__ k,
    const float* __restrict__ et, const float* __restrict__ kt,
    const float* __restrict__ ratios,
    ushort* __restrict__ M,
    float* __restrict__ rowsum,        // [4096], zeroed by k_init
    float* __restrict__ diag,          // [8][2048] exp values; slot 4 unused
    float* __restrict__ diagdot,       // [8][2048] raw dots;  slot 4 unused
    unsigned* __restrict__ grp,        // [64] per-128-row ready counters
    unsigned* __restrict__ tickets,    // [0]=prep ticket, [1]=done counter
    float* __restrict__ out)
{
  __shared__ ushort As[128 * 32];
  __shared__ ushort Bs[128 * 32];
  __shared__ float redR[256];
  __shared__ float redC[256];
  __shared__ unsigned s_rank;

  const int tid  = threadIdx.x;
  const int wave = tid >> 6;
  const int lane = tid & 63;

  // ---------------- PHASE A: work-stealing row normalization --------------
  // Task t: M row t (= array t>>11, batch row t&2047). Wave-level tickets.
  for (;;) {
    unsigned t;
    if (lane == 0)
      t = __hip_atomic_fetch_add(&tickets[0], 1u, __ATOMIC_RELAXED,
                                 __HIP_MEMORY_SCOPE_AGENT);
    t = (unsigned)__shfl((int)t, 0);
    if (t >= PREP_TASKS) break;
    const int tt = t >> 11, b = t & (NB - 1);
    const float* src = (tt == 0) ? e : (tt == 1) ? k : (tt == 2) ? et : kt;
    const float4* row = (const float4*)(src + (size_t)b * ND);
    float4 v0 = row[lane * 4 + 0], v1 = row[lane * 4 + 1];
    float4 v2 = row[lane * 4 + 2], v3 = row[lane * 4 + 3];
    float ss = v0.x*v0.x + v0.y*v0.y + v0.z*v0.z + v0.w*v0.w
             + v1.x*v1.x + v1.y*v1.y + v1.z*v1.z + v1.w*v1.w
             + v2.x*v2.x + v2.y*v2.y + v2.z*v2.z + v2.w*v2.w
             + v3.x*v3.x + v3.y*v3.y + v3.z*v3.z + v3.w*v3.w;
    #pragma unroll
    for (int o = 1; o < 64; o <<= 1) ss += __shfl_xor(ss, o);
    const float inv = 1.0f / sqrtf(ss);
    int4 w0, w1;
    w0.x = pack2_bf16(v0.x*inv, v0.y*inv); w0.y = pack2_bf16(v0.z*inv, v0.w*inv);
    w0.z = pack2_bf16(v1.x*inv, v1.y*inv); w0.w = pack2_bf16(v1.z*inv, v1.w*inv);
    w1.x = pack2_bf16(v2.x*inv, v2.y*inv); w1.y = pack2_bf16(v2.z*inv, v2.w*inv);
    w1.z = pack2_bf16(v3.x*inv, v3.y*inv); w1.w = pack2_bf16(v3.z*inv, v3.w*inv);
    ushort* dst = M + (size_t)t * ND + lane * 16;
    *(int4*)dst       = w0;
    *(int4*)(dst + 8) = w1;
    __threadfence();   // wave-wide drain + L2 writeback (agent scope)
    if (lane == 0)
      __hip_atomic_fetch_add(&grp[t >> 7], 1u, __ATOMIC_RELEASE,
                             __HIP_MEMORY_SCOPE_AGENT);
  }

  // ---------------- PHASE B: GEMM on this block's tile --------------------
  // decode (bx, by): 1024 right-half blocks + 528 upper-tri left-half blocks
  int bx, by;
  {
    int idx = blockIdx.x;
    if (idx < 1024) { by = idx >> 5; bx = 32 + (idx & 31); }
    else {
      int tr = idx - 1024; by = 0;
      while (tr >= 32 - by) { tr -= 32 - by; ++by; }
      bx = by + tr;
    }
  }
  const bool sym = (bx < 32) && (bx > by);
  const int j0 = bx * 128;
  const int i0 = by * 128;

  // wait until the 2 row-groups this tile needs are fully normalized
  if (tid == 0) {
    while (__hip_atomic_load(&grp[i0 >> 7], __ATOMIC_ACQUIRE,
                             __HIP_MEMORY_SCOPE_AGENT) < 128u)
      __builtin_amdgcn_s_sleep(1);
    while (__hip_atomic_load(&grp[j0 >> 7], __ATOMIC_ACQUIRE,
                             __HIP_MEMORY_SCOPE_AGENT) < 128u)
      __builtin_amdgcn_s_sleep(1);
  }
  __syncthreads();

  const int q = lane >> 4;       // quad 0..3
  const int m = lane & 15;       // row/col within 16
  const int wrow = (wave >> 1) * 64;
  const int wcol = (wave & 1) * 64;

  floatx4 acc[4][4] = {};

  // staging: chunk = 16 rows x 64 B; wave w stages chunks {2w,2w+1} of A,B.
  const int srow = lane >> 2;
  const int scol = (lane & 3) ^ ((srow >> 1) & 3);
  const int c0 = wave * 2, c1 = c0 + 1;

  const ushort* gA = M + (size_t)i0 * ND;
  const ushort* gB = M + (size_t)j0 * ND;

  int aoff[4], boff[4];
  #pragma unroll
  for (int x = 0; x < 4; ++x) {
    const int sw = (q ^ ((m >> 1) & 3)) * 8;
    aoff[x] = (wrow + x * 16 + m) * 32 + sw;
    boff[x] = (wcol + x * 16 + m) * 32 + sw;
  }

  for (int k0 = 0; k0 < ND; k0 += 32) {
    __syncthreads();
    {
      const ushort* g = gA + (size_t)(c0 * 16 + srow) * ND + k0 + scol * 8;
      __builtin_amdgcn_global_load_lds(
          (const __attribute__((address_space(1))) unsigned int*)g,
          (__attribute__((address_space(3))) unsigned int*)&As[c0 * 512], 16, 0, 0);
    }
    {
      const ushort* g = gA + (size_t)(c1 * 16 + srow) * ND + k0 + scol * 8;
      __builtin_amdgcn_global_load_lds(
          (const __attribute__((address_space(1))) unsigned int*)g,
          (__attribute__((address_space(3))) unsigned int*)&As[c1 * 512], 16, 0, 0);
    }
    {
      const ushort* g = gB + (size_t)(c0 * 16 + srow) * ND + k0 + scol * 8;
      __builtin_amdgcn_global_load_lds(
          (const __attribute__((address_space(1))) unsigned int*)g,
          (__attribute__((address_space(3))) unsigned int*)&Bs[c0 * 512], 16, 0, 0);
    }
    {
      const ushort* g = gB + (size_t)(c1 * 16 + srow) * ND + k0 + scol * 8;
      __builtin_amdgcn_global_load_lds(
          (const __attribute__((address_space(1))) unsigned int*)g,
          (__attribute__((address_space(3))) unsigned int*)&Bs[c1 * 512], 16, 0, 0);
    }
    __syncthreads();

    short8 af[4], bf[4];
    #pragma unroll
    for (int x = 0; x < 4; ++x) {
      af[x] = *(const short8*)&As[aoff[x]];
      bf[x] = *(const short8*)&Bs[boff[x]];
    }
    #pragma unroll
    for (int mi = 0; mi < 4; ++mi)
      #pragma unroll
      for (int ni = 0; ni < 4; ++ni)
        acc[mi][ni] = __builtin_amdgcn_mfma_f32_16x16x32_bf16(
            af[mi], bf[ni], acc[mi][ni], 0, 0, 0);
  }

  // Epilogue. C/D layout: col = lane&15, row = q*4 + reg  [m89/m91]
  float colAcc[4] = {0.f, 0.f, 0.f, 0.f};
  #pragma unroll
  for (int mi = 0; mi < 4; ++mi) {
    #pragma unroll
    for (int r = 0; r < 4; ++r) {
      const int ig = i0 + wrow + mi * 16 + q * 4 + r;
      float s = 0.f;
      #pragma unroll
      for (int ni = 0; ni < 4; ++ni) {
        float raw = acc[mi][ni][r];
        float v = __expf(raw * INV_TEMP);
        s += v;
        colAcc[ni] += v;
        const int jg = j0 + wcol + ni * 16 + m;
        if ((jg & (NB - 1)) == (ig & (NB - 1))) {
          const int slot = (((ig >> 11) << 2) + (jg >> 11)) * NB + (ig & (NB - 1));
          diag[slot] = v;
          diagdot[slot] = raw;
        }
      }
      s += __shfl_xor(s, 1);
      s += __shfl_xor(s, 2);
      s += __shfl_xor(s, 4);
      s += __shfl_xor(s, 8);
      if (m == 0) redR[(wave & 1) * 128 + wrow + mi * 16 + q * 4 + r] = s;
    }
  }
  #pragma unroll
  for (int ni = 0; ni < 4; ++ni) {
    float c = colAcc[ni];
    c += __shfl_xor(c, 16);
    c += __shfl_xor(c, 32);
    if (q == 0) redC[(wave >> 1) * 128 + wcol + ni * 16 + m] = c;
  }
  __syncthreads();
  if (tid < 128) {
    atomicAdd(&rowsum[i0 + tid], redR[tid] + redR[128 + tid]);
    if (sym)
      atomicAdd(&rowsum[j0 + tid], redC[tid] + redC[128 + tid]);
  }

  // completion: last finished block computes the final scalars
  __syncthreads();
  if (tid == 0) {
    __threadfence();
    s_rank = __hip_atomic_fetch_add(&tickets[1], 1u, __ATOMIC_ACQ_REL,
                                    __HIP_MEMORY_SCOPE_AGENT);
  }
  __syncthreads();
  if (s_rank == GEMM_BLOCKS - 1) {
    float l = 0.f, g = 0.f;
    #pragma unroll
    for (int i = 0; i < 8; ++i) {
      const int n = tid + i * 256;
      float se = __hip_atomic_load(&rowsum[n],        __ATOMIC_RELAXED, __HIP_MEMORY_SCOPE_AGENT);
      float sk = __hip_atomic_load(&rowsum[2048 + n], __ATOMIC_RELAXED, __HIP_MEMORY_SCOPE_AGENT);
      float d_ee  = diag[0 * NB + n];
      float d_ek  = diag[1 * NB + n];
      float d_eet = diag[2 * NB + n];
      float d_ekt = diag[3 * NB + n];
      float d_kk  = diag[5 * NB + n];
      float d_ket = diag[6 * NB + n];
      float d_kkt = diag[7 * NB + n];
      float num_e = d_ek + d_eet + d_ekt;
      float den_e = se - d_ee;
      float num_k = d_ek + d_ket + d_kkt;   // k.e diag == e.k diag (mirror)
      float den_k = sk - d_kk;
      l += logf(den_e / num_e) + logf(den_k / num_k);

      // cs-reg from Gram diagonals:
      // ||et - (r e + rm k)||^2 = 1 - 2(r c_eet + rm c_ket) + r^2+rm^2+2 r rm c_ek
      float c_ek  = diagdot[1 * NB + n];
      float c_eet = diagdot[2 * NB + n];
      float c_ekt = diagdot[3 * NB + n];
      float c_ket = diagdot[6 * NB + n];
      float c_kkt = diagdot[7 * NB + n];
      float r  = ratios[n], rm = 1.0f - r;
      float an = r * r + rm * rm + 2.0f * r * rm * c_ek;
      float q1 = 1.0f - 2.0f * (r * c_eet + rm * c_ket) + an;
      float q2 = 1.0f - 2.0f * (rm * c_ekt + r * c_kkt) + an;
      g += sqrtf(fmaxf(q1, 0.0f)) + sqrtf(fmaxf(q2, 0.0f));
    }
    #pragma unroll
    for (int o = 1; o < 64; o <<= 1) { l += __shfl_xor(l, o); g += __shfl_xor(g, o); }
    if ((tid & 63) == 0) { redR[tid >> 6] = l; redC[tid >> 6] = g; }
    __syncthreads();
    if (tid == 0) {
      float contrastive = (redR[0] + redR[1] + redR[2] + redR[3]) * (1.0f / (2.0f * NB));
      float cs = (redC[0] + redC[1] + redC[2] + redC[3]) * (1.0f / NB);
      out[0] = contrastive + LAMBDA_CS * cs;
      out[1] = contrastive;
      out[2] = cs;
    }
  }
}

// ---------------------------------------------------------------------------
extern "C" void kernel_launch(void* const* d_in, const int* in_sizes, int n_in,
                              void* d_out, int out_size, void* d_ws, size_t ws_size,
                              hipStream_t stream) {
  const float* english = (const float*)d_in[0];
  const float* etok    = (const float*)d_in[1];
  const float* ktoe    = (const float*)d_in[2];
  const float* korean  = (const float*)d_in[3];
  const float* ratios  = (const float*)d_in[4];

  char* ws = (char*)d_ws;
  const size_t OFF_M    = 0;                                    // 16 MB
  const size_t OFF_RS   = OFF_M + (size_t)8192 * 1024 * 2;      // 4096*4
  const size_t OFF_DIAG = OFF_RS + 4096 * sizeof(float);        // 8*2048*4
  const size_t OFF_DDOT = OFF_DIAG + 8 * NB * sizeof(float);    // 8*2048*4
  const size_t OFF_GRP  = OFF_DDOT + 8 * NB * sizeof(float);    // 64*4
  const size_t OFF_TKT  = OFF_GRP + 64 * sizeof(unsigned);      // 2*4

  ushort* M           = (ushort*)(ws + OFF_M);
  float* rowsum       = (float*)(ws + OFF_RS);
  float* diag         = (float*)(ws + OFF_DIAG);
  float* diagdot      = (float*)(ws + OFF_DDOT);
  unsigned* grp       = (unsigned*)(ws + OFF_GRP);
  unsigned* tickets   = (unsigned*)(ws + OFF_TKT);

  k_init<<<dim3(17), 256, 0, stream>>>(rowsum, grp, tickets);
  k_main<<<dim3(GEMM_BLOCKS), 256, 0, stream>>>(
      english, korean, etok, ktoe, ratios, M, rowsum, diag, diagdot,
      grp, tickets, (float*)d_out);
}